// Round 10
// baseline (301.218 us; speedup 1.0000x reference)
//
#include <hip/hip_runtime.h>
#include <math.h>

#define N_NODES 100000
#define N_EDGES 1600000
#define F 128
#define NBUCK 391        // buckets of 256 rows
#define EPB 4096         // edges per bucketize block (391 blocks)
#define CAP 4800         // bucket region capacity (avg 4096, +11 sigma)

#define XCH512 (N_NODES * F / 8 / 512)   // 3125 convert-x chunks
#define WCH512 (F * F / 2 / 512)         // 16 convert-w chunks

typedef _Float16 f16x2 __attribute__((ext_vector_type(2)));
typedef _Float16 f16x8 __attribute__((ext_vector_type(8)));
typedef __fp16 fp16x2 __attribute__((ext_vector_type(2)));
typedef float f32x2 __attribute__((ext_vector_type(2)));
typedef float f32x4 __attribute__((ext_vector_type(4)));

__device__ inline uint pkrtz(float a, float b) {
    union { fp16x2 h; uint u; } c;
    c.h = __builtin_amdgcn_cvt_pkrtz(a, b);
    return c.u;
}
__device__ inline f16x2 as2(uint u) {
    union { uint u; f16x2 h; } c; c.u = u; return c.h;
}

__device__ inline int wave_incl_scan(int v, int lane) {
#pragma unroll
    for (int off = 1; off < 64; off <<= 1) {
        int t = __shfl_up(v, off);
        if (lane >= off) v += t;
    }
    return v;
}

// ---------------- mega kernel: bucketize (blocks 0..390) + convert_x
// (391..3515) + convert_w (3516..3531). Converts backfill bucketize's idle
// CUs. Bucket-local LDS atomics + block-aggregated cursors (R5 post-mortem:
// global scattered returning atomics were 6x slower). ----------------

__global__ __launch_bounds__(512) void build_convert_kernel(
        const int* __restrict__ row, const int* __restrict__ col,
        int* __restrict__ bucket_cursor, int* __restrict__ pairs,
        const float* __restrict__ X, const float* __restrict__ W1,
        const float* __restrict__ W2, uint* __restrict__ Xh,
        uint* __restrict__ W1h, uint* __restrict__ W2h) {
    __shared__ int stage[EPB];
    __shared__ ushort bid[EPB];
    __shared__ int lcnt[NBUCK], lcur[NBUCK], loff[NBUCK], gbase[NBUCK];
    __shared__ int wsum[8];
    const int blk = blockIdx.x;
    const int tid = threadIdx.x;

    if (blk >= NBUCK) {
        if (blk < NBUCK + XCH512) {
            int i = (blk - NBUCK) * 512 + tid;   // chunk of 8 floats, exact
            float4 a = *(const float4*)&X[(size_t)i * 8];
            float4 c = *(const float4*)&X[(size_t)i * 8 + 4];
            uint4 o = {pkrtz(a.x, a.y), pkrtz(a.z, a.w), pkrtz(c.x, c.y), pkrtz(c.z, c.w)};
            *(uint4*)&Xh[(size_t)i * 4] = o;
        } else {
            int i = (blk - NBUCK - XCH512) * 512 + tid;   // pair index, exact
            float2 a = *(const float2*)&W1[i * 2];
            float2 c = *(const float2*)&W2[i * 2];
            W1h[i] = pkrtz(a.x, a.y);
            W2h[i] = pkrtz(c.x, c.y);
        }
        return;
    }

    // ---- bucketize branch ----
    const int lane = tid & 63;
    const int wid = tid >> 6;
    const int base = blk * EPB;
    const int cnt = min(N_EDGES - base, EPB);

    for (int i = tid; i < NBUCK; i += 512) { lcnt[i] = 0; lcur[i] = 0; }
    __syncthreads();
    for (int i = 0; i < EPB / 512; ++i) {
        int e = base + i * 512 + tid;
        if (e < N_EDGES) atomicAdd(&lcnt[row[e] >> 8], 1);
    }
    __syncthreads();
    {   // exclusive scan of lcnt -> loff (wave scan + 8-wave combine)
        int v = (tid < NBUCK) ? lcnt[tid] : 0;
        int inc = wave_incl_scan(v, lane);
        if (lane == 63) wsum[wid] = inc;
        __syncthreads();
        if (tid == 0) {
            int a = 0;
#pragma unroll
            for (int i = 0; i < 8; ++i) { int t = wsum[i]; wsum[i] = a; a += t; }
        }
        __syncthreads();
        if (tid < NBUCK) loff[tid] = inc - v + wsum[wid];
    }
    if (tid < NBUCK) {
        int c = lcnt[tid];
        gbase[tid] = c ? atomicAdd(&bucket_cursor[tid], c) : 0;
    }
    __syncthreads();
    for (int i = 0; i < EPB / 512; ++i) {
        int e = base + i * 512 + tid;
        if (e < N_EDGES) {
            int r = row[e], c = col[e];
            int b = r >> 8;
            int rk = atomicAdd(&lcur[b], 1);
            int q = loff[b] + rk;
            stage[q] = ((r & 255) << 17) | c;   // 8b local row | 17b col
            bid[q] = (ushort)b;
        }
    }
    __syncthreads();
    for (int q = tid; q < cnt; q += 512) {
        int b = bid[q];
        int t = gbase[b] + (q - loff[b]);
        if (t < CAP) pairs[b * CAP + t] = stage[q];
    }
}

// finalize: 391 blocks x 1024 thr. R10: also emits perm[] -- nodes of each
// 256-window counting-sorted by degree (64 bins, LDS) so every 16-node fused
// block draws near-equal-degree nodes (kills the E[max of 16 Poisson(16)]=26
// vs mean=16 within-block gather tail; cross-block imbalance is free via
// backfill). Invalid tail rows binned 63 -> sorted past index N_NODES-1.
__global__ __launch_bounds__(1024) void csr_finalize_kernel(const int* __restrict__ pairs,
                                                            const int* __restrict__ bucket_cursor,
                                                            int* __restrict__ csr_col,
                                                            int2* __restrict__ rs,
                                                            float* __restrict__ deg_inv,
                                                            int* __restrict__ perm) {
    __shared__ int rcnt[256], rcnt2[256], roff[256];
    __shared__ int colstage[CAP];
    __shared__ int wsum[4];
    __shared__ int hist[64], hcur[64], hoff[64];
    const int tid = threadIdx.x;
    const int lane = tid & 63;
    const int wid = tid >> 6;
    const int b = blockIdx.x;
    const int cnt = min(bucket_cursor[b], CAP);
    const int base = b * CAP;
    const int* reg = &pairs[base];

    if (tid < 256) { rcnt[tid] = 0; rcnt2[tid] = 0; }
    if (tid < 64) { hist[tid] = 0; hcur[tid] = 0; }
    __syncthreads();
    for (int q = tid; q < cnt; q += 1024) atomicAdd(&rcnt[reg[q] >> 17], 1);
    __syncthreads();
    int d = 0, inc = 0, bin = 63;
    const int grow = (b << 8) + tid;
    if (tid < 256) {
        d = rcnt[tid];
        inc = wave_incl_scan(d, lane);
        if (lane == 63) wsum[wid] = inc;   // wid 0..3
        bin = (grow < N_NODES) ? min(d, 62) : 63;
        atomicAdd(&hist[bin], 1);
    }
    __syncthreads();
    if (tid == 0) {
        int a = 0;
#pragma unroll
        for (int i = 0; i < 4; ++i) { int t = wsum[i]; wsum[i] = a; a += t; }
    }
    if (tid < 64) {   // wave-0 scan of 64-bin histogram
        int v = hist[tid];
        int hi = wave_incl_scan(v, tid);
        hoff[tid] = hi - v;
    }
    __syncthreads();
    if (tid < 256) {
        const int excl = inc - d + wsum[wid];
        roff[tid] = excl;
        if (grow < N_NODES) {
            rs[grow] = make_int2(base + excl, d);
            deg_inv[grow] = d ? 1.0f / (float)d : 0.0f;
        }
        int rank = hoff[bin] + atomicAdd(&hcur[bin], 1);
        perm[(b << 8) + rank] = grow;
    }
    __syncthreads();
    for (int q = tid; q < cnt; q += 1024) {
        int v = reg[q];
        int lr = v >> 17;
        int rk = atomicAdd(&rcnt2[lr], 1);
        colstage[roff[lr] + rk] = v & 0x1FFFF;
    }
    __syncthreads();
    for (int q = tid; q < cnt; q += 1024) csr_col[base + q] = colstage[q];
}

// ---------------- fused mean-agg + MFMA GEMM ----------------
// Legality: D^-1 A (H W^T + 1 b^T) = (D^-1 A H) W^T + mask.b^T  (mask = deg>0).
// Block = 16 nodes via perm[] (degree-equalized, R10); each 16-lane group
// gathers ONE node; GEMM split by output-feature across waves.
// f16 epilogue bounces through LDS -> 4KB contiguous (per-row 256B chunks
// with perm -- still line-complete); f32: wave's 128B/node = full lines.

template <bool ELU, bool OUT_F32>
__global__ __launch_bounds__(256, 6) void fused_agg_gemm_kernel(
        const ushort* __restrict__ H,
        const int2* __restrict__ rs,
        const int* __restrict__ csr_col,
        const float* __restrict__ deg_inv,
        const int* __restrict__ perm,
        const ushort* __restrict__ Wh,
        const float* __restrict__ bias,
        void* __restrict__ out) {
    __shared__ __align__(16) ushort xs[16 * 136];     // 16 agg rows, pitch 136

    const int tid = threadIdx.x;                      // 0..255
    const int m0 = blockIdx.x << 4;                   // 16 perm-slots per block
    const int g = tid >> 4;                           // 16-lane group = slot 0..15
    const int fo = (tid & 15) << 3;                   // ushort feature offset
    const int nodeA = perm[m0 + g];                   // this group's node (valid)

    // ---- phase A: gather-aggregate ONE node per 16-lane group ----
    {
        f32x2 a[4];
#pragma unroll
        for (int i = 0; i < 4; ++i) a[i] = (f32x2){0.f, 0.f};
        const int2 sd = rs[nodeA];
        int p = sd.x;
        const int e = sd.x + sd.y;
        const float di = deg_inv[nodeA];
        if (p + 7 < e) {
            int cc[8];
#pragma unroll
            for (int k = 0; k < 8; ++k) cc[k] = __builtin_nontemporal_load(&csr_col[p + k]);
            while (true) {
                uint4 vv[8];
#pragma unroll
                for (int k = 0; k < 8; ++k) vv[k] = *(const uint4*)&H[(size_t)cc[k] * F + fo];
                p += 8;
                const bool more = (p + 7 < e);
                int cn[8];
                if (more) {
#pragma unroll
                    for (int k = 0; k < 8; ++k) cn[k] = __builtin_nontemporal_load(&csr_col[p + k]);
                }
                asm volatile("" :: "v"(vv[0].x), "v"(vv[1].x), "v"(vv[2].x), "v"(vv[3].x),
                                   "v"(vv[4].x), "v"(vv[5].x), "v"(vv[6].x), "v"(vv[7].x));
#pragma unroll
                for (int k = 0; k < 8; k += 4) {
                    f16x2 h0 = (as2(vv[k].x) + as2(vv[k + 1].x)) + (as2(vv[k + 2].x) + as2(vv[k + 3].x));
                    f16x2 h1 = (as2(vv[k].y) + as2(vv[k + 1].y)) + (as2(vv[k + 2].y) + as2(vv[k + 3].y));
                    f16x2 h2 = (as2(vv[k].z) + as2(vv[k + 1].z)) + (as2(vv[k + 2].z) + as2(vv[k + 3].z));
                    f16x2 h3 = (as2(vv[k].w) + as2(vv[k + 1].w)) + (as2(vv[k + 2].w) + as2(vv[k + 3].w));
                    a[0] += (f32x2){(float)h0.x, (float)h0.y};
                    a[1] += (f32x2){(float)h1.x, (float)h1.y};
                    a[2] += (f32x2){(float)h2.x, (float)h2.y};
                    a[3] += (f32x2){(float)h3.x, (float)h3.y};
                }
                if (!more) break;
#pragma unroll
                for (int k = 0; k < 8; ++k) cc[k] = cn[k];
            }
        }
        if (p + 3 < e) {
            int c0 = csr_col[p], c1 = csr_col[p + 1], c2 = csr_col[p + 2], c3 = csr_col[p + 3];
            uint4 v0 = *(const uint4*)&H[(size_t)c0 * F + fo];
            uint4 v1 = *(const uint4*)&H[(size_t)c1 * F + fo];
            uint4 v2 = *(const uint4*)&H[(size_t)c2 * F + fo];
            uint4 v3 = *(const uint4*)&H[(size_t)c3 * F + fo];
            f16x2 h0 = (as2(v0.x) + as2(v1.x)) + (as2(v2.x) + as2(v3.x));
            f16x2 h1 = (as2(v0.y) + as2(v1.y)) + (as2(v2.y) + as2(v3.y));
            f16x2 h2 = (as2(v0.z) + as2(v1.z)) + (as2(v2.z) + as2(v3.z));
            f16x2 h3 = (as2(v0.w) + as2(v1.w)) + (as2(v2.w) + as2(v3.w));
            a[0] += (f32x2){(float)h0.x, (float)h0.y};
            a[1] += (f32x2){(float)h1.x, (float)h1.y};
            a[2] += (f32x2){(float)h2.x, (float)h2.y};
            a[3] += (f32x2){(float)h3.x, (float)h3.y};
            p += 4;
        }
        if (p + 1 < e) {
            int c0 = csr_col[p], c1 = csr_col[p + 1];
            uint4 v0 = *(const uint4*)&H[(size_t)c0 * F + fo];
            uint4 v1 = *(const uint4*)&H[(size_t)c1 * F + fo];
            f16x2 h0 = as2(v0.x) + as2(v1.x);
            f16x2 h1 = as2(v0.y) + as2(v1.y);
            f16x2 h2 = as2(v0.z) + as2(v1.z);
            f16x2 h3 = as2(v0.w) + as2(v1.w);
            a[0] += (f32x2){(float)h0.x, (float)h0.y};
            a[1] += (f32x2){(float)h1.x, (float)h1.y};
            a[2] += (f32x2){(float)h2.x, (float)h2.y};
            a[3] += (f32x2){(float)h3.x, (float)h3.y};
            p += 2;
        }
        if (p < e) {
            int c = csr_col[p];
            uint4 v = *(const uint4*)&H[(size_t)c * F + fo];
            f16x2 h0 = as2(v.x), h1 = as2(v.y), h2 = as2(v.z), h3 = as2(v.w);
            a[0] += (f32x2){(float)h0.x, (float)h0.y};
            a[1] += (f32x2){(float)h1.x, (float)h1.y};
            a[2] += (f32x2){(float)h2.x, (float)h2.y};
            a[3] += (f32x2){(float)h3.x, (float)h3.y};
        }
        uint4 o = {pkrtz(a[0].x * di, a[0].y * di), pkrtz(a[1].x * di, a[1].y * di),
                   pkrtz(a[2].x * di, a[2].y * di), pkrtz(a[3].x * di, a[3].y * di)};
        *(uint4*)&xs[g * 136 + fo] = o;
    }
    __syncthreads();   // #1: xs complete

    // ---- phase B: MFMA Y^T = W @ g^T, split by output-feature across waves ----
    const int w = tid >> 6;        // wave 0..3 owns j in {2w, 2w+1}
    const int lane = tid & 63;
    const int q = lane >> 4;
    const int t = lane & 15;
    const int nodeB = perm[m0 + t];

    f16x8 xfr[4];
#pragma unroll
    for (int kk = 0; kk < 4; ++kk)
        xfr[kk] = *(const f16x8*)&xs[t * 136 + kk * 32 + q * 8];

    if (!OUT_F32) __syncthreads();   // #2: all xs reads done before ys overlay

    const float dv = deg_inv[nodeB];
    const float mk = (dv > 0.f) ? 1.f : 0.f;

    f32x4 vout[2];
#pragma unroll
    for (int jj = 0; jj < 2; ++jj) {
        const int j = (w << 1) | jj;
        f32x4 acc = (f32x4){0.f, 0.f, 0.f, 0.f};
        const ushort* wrow = &Wh[(j * 16 + t) * F + q * 8];
#pragma unroll
        for (int kk = 0; kk < 4; ++kk) {
            f16x8 wfr = *(const f16x8*)&wrow[kk * 32];
            acc = __builtin_amdgcn_mfma_f32_16x16x32_f16(wfr, xfr[kk], acc, 0, 0, 0);
        }
        f32x4 bb = *(const f32x4*)&bias[j * 16 + q * 4];
        f32x4 v = acc + bb * mk;
        if (ELU) {
#pragma unroll
            for (int r = 0; r < 4; ++r) v[r] = (v[r] > 0.f) ? v[r] : expm1f(v[r]);
        }
        vout[jj] = v;
    }

    if (OUT_F32) {
        // wave's 128B per node = one full line: direct stores are line-complete
        float* of = &((float*)out)[(size_t)nodeB * F + (w << 5) + q * 4];
        __builtin_nontemporal_store(vout[0], (f32x4*)of);
        __builtin_nontemporal_store(vout[1], (f32x4*)(of + 16));
    } else {
        // bounce through LDS (xs reused) -> per-row 256B contiguous stores
        ushort* ys = xs;
        uint2 o0 = {pkrtz(vout[0][0], vout[0][1]), pkrtz(vout[0][2], vout[0][3])};
        uint2 o1 = {pkrtz(vout[1][0], vout[1][1]), pkrtz(vout[1][2], vout[1][3])};
        *(uint2*)&ys[t * 136 + (w << 5) + q * 4] = o0;
        *(uint2*)&ys[t * 136 + (w << 5) + 16 + q * 4] = o1;
        __syncthreads();   // #3
        const int n2 = tid >> 4, seg = tid & 15;   // n2 == g -> nodeA
        uint4 vo = *(const uint4*)&ys[n2 * 136 + seg * 8];
        __builtin_nontemporal_store(*(f32x4*)&vo,
            (f32x4*)&((ushort*)out)[(size_t)nodeA * F + seg * 8]);
    }
}

// ---------------- launch ----------------

extern "C" void kernel_launch(void* const* d_in, const int* in_sizes, int n_in,
                              void* d_out, int out_size, void* d_ws, size_t ws_size,
                              hipStream_t stream) {
    const float* x  = (const float*)d_in[0];
    const int*   ei = (const int*)d_in[1];
    const float* W1 = (const float*)d_in[2];
    const float* b1 = (const float*)d_in[3];
    const float* W2 = (const float*)d_in[4];
    const float* b2 = (const float*)d_in[5];
    float* out = (float*)d_out;

    const int* row = ei;
    const int* col = ei + N_EDGES;

    // workspace layout (16B-aligned)
    ushort* bufA = (ushort*)d_ws;                            // N*F f16 (h1, 25.6 MB)
    ushort* bufB = bufA + (size_t)N_NODES * F;               // N*F f16 (Xh)
    int* csr_col = (int*)(bufB + (size_t)N_NODES * F);       // NBUCK*CAP (7.5 MB)
    int2* rs = (int2*)(csr_col + NBUCK * CAP);               // N {start,deg}
    float* deg_inv = (float*)(rs + N_NODES + 4);             // N
    int* perm = (int*)(deg_inv + N_NODES);                   // NBUCK*256 = 100096
    int* bucket_cursor = perm + NBUCK * 256;                 // 512
    uint* W1h = (uint*)(bucket_cursor + 512);                // 8192 uints
    uint* W2h = W1h + F * F / 2;                             // 8192 uints
    int* pairs = (int*)bufA;  // 7.5 MB overlay, dead before fused layer 1 writes bufA

    // build + converts (converts backfill bucketize's idle CUs)
    (void)hipMemsetAsync(bucket_cursor, 0, 512 * sizeof(int), stream);
    build_convert_kernel<<<NBUCK + XCH512 + WCH512, 512, 0, stream>>>(
        row, col, bucket_cursor, pairs, x, W1, W2, (uint*)bufB, W1h, W2h);
    csr_finalize_kernel<<<NBUCK, 1024, 0, stream>>>(pairs, bucket_cursor, csr_col, rs, deg_inv, perm);

    const int fb = N_NODES / 16;   // 6250, exact
    // layer 1: h1 = elu( agg(Xh) @ W1^T + mask*b1 ), f16 out
    fused_agg_gemm_kernel<true, false><<<fb, 256, 0, stream>>>(
        (const ushort*)bufB, rs, csr_col, deg_inv, perm, (const ushort*)W1h, b1, bufA);
    // layer 2: out = agg(h1) @ W2^T + mask*b2, f32 out
    fused_agg_gemm_kernel<false, true><<<fb, 256, 0, stream>>>(
        bufA, rs, csr_col, deg_inv, perm, (const ushort*)W2h, b2, out);
}

// Round 11
// 271.135 us; speedup vs baseline: 1.1110x; 1.1110x over previous
//
#include <hip/hip_runtime.h>
#include <math.h>

#define N_NODES 100000
#define N_EDGES 1600000
#define F 128
#define NBUCK 391        // buckets of 256 rows
#define EPB 4096         // edges per bucketize block (391 blocks)
#define CAP 4800         // bucket region capacity (avg 4096, +11 sigma)

#define XCH512 (N_NODES * F / 8 / 512)   // 3125 convert-x chunks
#define WCH512 (F * F / 2 / 512)         // 16 convert-w chunks

typedef _Float16 f16x2 __attribute__((ext_vector_type(2)));
typedef _Float16 f16x8 __attribute__((ext_vector_type(8)));
typedef __fp16 fp16x2 __attribute__((ext_vector_type(2)));
typedef float f32x2 __attribute__((ext_vector_type(2)));
typedef float f32x4 __attribute__((ext_vector_type(4)));

__device__ inline uint pkrtz(float a, float b) {
    union { fp16x2 h; uint u; } c;
    c.h = __builtin_amdgcn_cvt_pkrtz(a, b);
    return c.u;
}
__device__ inline f16x2 as2(uint u) {
    union { uint u; f16x2 h; } c; c.u = u; return c.h;
}

__device__ inline int wave_incl_scan(int v, int lane) {
#pragma unroll
    for (int off = 1; off < 64; off <<= 1) {
        int t = __shfl_up(v, off);
        if (lane >= off) v += t;
    }
    return v;
}

// ---------------- mega kernel: bucketize (blocks 0..390) + convert_x
// (391..3515) + convert_w (3516..3531). Converts backfill bucketize's idle
// CUs. Bucket-local LDS atomics + block-aggregated cursors (R5 post-mortem:
// global scattered returning atomics were 6x slower). ----------------

__global__ __launch_bounds__(512) void build_convert_kernel(
        const int* __restrict__ row, const int* __restrict__ col,
        int* __restrict__ bucket_cursor, int* __restrict__ pairs,
        const float* __restrict__ X, const float* __restrict__ W1,
        const float* __restrict__ W2, uint* __restrict__ Xh,
        uint* __restrict__ W1h, uint* __restrict__ W2h) {
    __shared__ int stage[EPB];
    __shared__ ushort bid[EPB];
    __shared__ int lcnt[NBUCK], lcur[NBUCK], loff[NBUCK], gbase[NBUCK];
    __shared__ int wsum[8];
    const int blk = blockIdx.x;
    const int tid = threadIdx.x;

    if (blk >= NBUCK) {
        if (blk < NBUCK + XCH512) {
            int i = (blk - NBUCK) * 512 + tid;   // chunk of 8 floats, exact
            float4 a = *(const float4*)&X[(size_t)i * 8];
            float4 c = *(const float4*)&X[(size_t)i * 8 + 4];
            uint4 o = {pkrtz(a.x, a.y), pkrtz(a.z, a.w), pkrtz(c.x, c.y), pkrtz(c.z, c.w)};
            *(uint4*)&Xh[(size_t)i * 4] = o;
        } else {
            int i = (blk - NBUCK - XCH512) * 512 + tid;   // pair index, exact
            float2 a = *(const float2*)&W1[i * 2];
            float2 c = *(const float2*)&W2[i * 2];
            W1h[i] = pkrtz(a.x, a.y);
            W2h[i] = pkrtz(c.x, c.y);
        }
        return;
    }

    // ---- bucketize branch ----
    const int lane = tid & 63;
    const int wid = tid >> 6;
    const int base = blk * EPB;
    const int cnt = min(N_EDGES - base, EPB);

    for (int i = tid; i < NBUCK; i += 512) { lcnt[i] = 0; lcur[i] = 0; }
    __syncthreads();
    for (int i = 0; i < EPB / 512; ++i) {
        int e = base + i * 512 + tid;
        if (e < N_EDGES) atomicAdd(&lcnt[row[e] >> 8], 1);
    }
    __syncthreads();
    {   // exclusive scan of lcnt -> loff (wave scan + 8-wave combine)
        int v = (tid < NBUCK) ? lcnt[tid] : 0;
        int inc = wave_incl_scan(v, lane);
        if (lane == 63) wsum[wid] = inc;
        __syncthreads();
        if (tid == 0) {
            int a = 0;
#pragma unroll
            for (int i = 0; i < 8; ++i) { int t = wsum[i]; wsum[i] = a; a += t; }
        }
        __syncthreads();
        if (tid < NBUCK) loff[tid] = inc - v + wsum[wid];
    }
    if (tid < NBUCK) {
        int c = lcnt[tid];
        gbase[tid] = c ? atomicAdd(&bucket_cursor[tid], c) : 0;
    }
    __syncthreads();
    for (int i = 0; i < EPB / 512; ++i) {
        int e = base + i * 512 + tid;
        if (e < N_EDGES) {
            int r = row[e], c = col[e];
            int b = r >> 8;
            int rk = atomicAdd(&lcur[b], 1);
            int q = loff[b] + rk;
            stage[q] = ((r & 255) << 17) | c;   // 8b local row | 17b col
            bid[q] = (ushort)b;
        }
    }
    __syncthreads();
    for (int q = tid; q < cnt; q += 512) {
        int b = bid[q];
        int t = gbase[b] + (q - loff[b]);
        if (t < CAP) pairs[b * CAP + t] = stage[q];
    }
}

// finalize: 391 blocks x 1024 thr. R11: single global read -- pairs staged
// into LDS once (coalesced), histogram + scatter then run at LDS latency
// (was: two strided global read passes at ~600ns/iter chains, 1.53 blk/CU).
__global__ __launch_bounds__(1024) void csr_finalize_kernel(const int* __restrict__ pairs,
                                                            const int* __restrict__ bucket_cursor,
                                                            int* __restrict__ csr_col,
                                                            int2* __restrict__ rs,
                                                            float* __restrict__ deg_inv) {
    __shared__ int stage2[CAP];
    __shared__ int colstage[CAP];
    __shared__ int rcnt[256], rcnt2[256], roff[256];
    __shared__ int wsum[4];
    const int tid = threadIdx.x;
    const int lane = tid & 63;
    const int wid = tid >> 6;
    const int b = blockIdx.x;
    const int cnt = min(bucket_cursor[b], CAP);
    const int base = b * CAP;

    if (tid < 256) { rcnt[tid] = 0; rcnt2[tid] = 0; }
    for (int q = tid; q < cnt; q += 1024) stage2[q] = pairs[base + q];
    __syncthreads();
    for (int q = tid; q < cnt; q += 1024) atomicAdd(&rcnt[stage2[q] >> 17], 1);
    __syncthreads();
    int d = 0, inc = 0;
    if (tid < 256) {
        d = rcnt[tid];
        inc = wave_incl_scan(d, lane);
        if (lane == 63) wsum[wid] = inc;   // wid 0..3
    }
    __syncthreads();
    if (tid == 0) {
        int a = 0;
#pragma unroll
        for (int i = 0; i < 4; ++i) { int t = wsum[i]; wsum[i] = a; a += t; }
    }
    __syncthreads();
    if (tid < 256) {
        const int excl = inc - d + wsum[wid];
        roff[tid] = excl;
        const int grow = (b << 8) + tid;
        if (grow < N_NODES) {
            rs[grow] = make_int2(base + excl, d);
            deg_inv[grow] = d ? 1.0f / (float)d : 0.0f;
        }
    }
    __syncthreads();
    for (int q = tid; q < cnt; q += 1024) {
        int v = stage2[q];
        int lr = v >> 17;
        int rk = atomicAdd(&rcnt2[lr], 1);
        colstage[roff[lr] + rk] = v & 0x1FFFF;
    }
    __syncthreads();
    for (int q = tid; q < cnt; q += 1024) csr_col[base + q] = colstage[q];
}

// ---------------- fused mean-agg + MFMA GEMM ----------------
// Legality: D^-1 A (H W^T + 1 b^T) = (D^-1 A H) W^T + mask.b^T  (mask = deg>0).
// Block = 16 consecutive nodes (R10 post-mortem: degree-sorted perm REGRESSED
// 15us -- it scattered rs/csr_col streaming and created systematic inter-block
// tails; identity order restored). Each 16-lane group gathers ONE node;
// GEMM split by output-feature across waves.
// f16 epilogue bounces through LDS -> 4KB contiguous (cross-wave 128B-line
// sharing made register stores half-dirty, R8: WRITE 56 vs 25.6 ideal);
// f32: wave's 128B/node = full lines -> direct stores.
// R11: launch_bounds (256,8) -- VGPR 32 fits the 64-cap; frees the 6-block
// occupancy hint (R9 measured 75% at hint 6).

template <bool ELU, bool OUT_F32>
__global__ __launch_bounds__(256, 8) void fused_agg_gemm_kernel(
        const ushort* __restrict__ H,
        const int2* __restrict__ rs,
        const int* __restrict__ csr_col,
        const float* __restrict__ deg_inv,
        const ushort* __restrict__ Wh,
        const float* __restrict__ bias,
        void* __restrict__ out) {
    __shared__ __align__(16) ushort xs[16 * 136];     // 16 agg rows, pitch 136

    const int tid = threadIdx.x;                      // 0..255
    const int m0 = blockIdx.x << 4;                   // 16 nodes per block
    const int g = tid >> 4;                           // 16-lane group = node 0..15
    const int fo = (tid & 15) << 3;                   // ushort feature offset

    // ---- phase A: gather-aggregate ONE node per 16-lane group ----
    {
        const int node = m0 + g;
        f32x2 a[4];
#pragma unroll
        for (int i = 0; i < 4; ++i) a[i] = (f32x2){0.f, 0.f};
        const int2 sd = rs[node];
        int p = sd.x;
        const int e = sd.x + sd.y;
        const float di = deg_inv[node];
        if (p + 7 < e) {
            int cc[8];
#pragma unroll
            for (int k = 0; k < 8; ++k) cc[k] = __builtin_nontemporal_load(&csr_col[p + k]);
            while (true) {
                uint4 vv[8];
#pragma unroll
                for (int k = 0; k < 8; ++k) vv[k] = *(const uint4*)&H[(size_t)cc[k] * F + fo];
                p += 8;
                const bool more = (p + 7 < e);
                int cn[8];
                if (more) {
#pragma unroll
                    for (int k = 0; k < 8; ++k) cn[k] = __builtin_nontemporal_load(&csr_col[p + k]);
                }
                // pin: all 8 H-loads issued (and jointly waited) here
                asm volatile("" :: "v"(vv[0].x), "v"(vv[1].x), "v"(vv[2].x), "v"(vv[3].x),
                                   "v"(vv[4].x), "v"(vv[5].x), "v"(vv[6].x), "v"(vv[7].x));
#pragma unroll
                for (int k = 0; k < 8; k += 4) {
                    f16x2 h0 = (as2(vv[k].x) + as2(vv[k + 1].x)) + (as2(vv[k + 2].x) + as2(vv[k + 3].x));
                    f16x2 h1 = (as2(vv[k].y) + as2(vv[k + 1].y)) + (as2(vv[k + 2].y) + as2(vv[k + 3].y));
                    f16x2 h2 = (as2(vv[k].z) + as2(vv[k + 1].z)) + (as2(vv[k + 2].z) + as2(vv[k + 3].z));
                    f16x2 h3 = (as2(vv[k].w) + as2(vv[k + 1].w)) + (as2(vv[k + 2].w) + as2(vv[k + 3].w));
                    a[0] += (f32x2){(float)h0.x, (float)h0.y};
                    a[1] += (f32x2){(float)h1.x, (float)h1.y};
                    a[2] += (f32x2){(float)h2.x, (float)h2.y};
                    a[3] += (f32x2){(float)h3.x, (float)h3.y};
                }
                if (!more) break;
#pragma unroll
                for (int k = 0; k < 8; ++k) cc[k] = cn[k];
            }
        }
        if (p + 3 < e) {
            int c0 = csr_col[p], c1 = csr_col[p + 1], c2 = csr_col[p + 2], c3 = csr_col[p + 3];
            uint4 v0 = *(const uint4*)&H[(size_t)c0 * F + fo];
            uint4 v1 = *(const uint4*)&H[(size_t)c1 * F + fo];
            uint4 v2 = *(const uint4*)&H[(size_t)c2 * F + fo];
            uint4 v3 = *(const uint4*)&H[(size_t)c3 * F + fo];
            f16x2 h0 = (as2(v0.x) + as2(v1.x)) + (as2(v2.x) + as2(v3.x));
            f16x2 h1 = (as2(v0.y) + as2(v1.y)) + (as2(v2.y) + as2(v3.y));
            f16x2 h2 = (as2(v0.z) + as2(v1.z)) + (as2(v2.z) + as2(v3.z));
            f16x2 h3 = (as2(v0.w) + as2(v1.w)) + (as2(v2.w) + as2(v3.w));
            a[0] += (f32x2){(float)h0.x, (float)h0.y};
            a[1] += (f32x2){(float)h1.x, (float)h1.y};
            a[2] += (f32x2){(float)h2.x, (float)h2.y};
            a[3] += (f32x2){(float)h3.x, (float)h3.y};
            p += 4;
        }
        if (p + 1 < e) {
            int c0 = csr_col[p], c1 = csr_col[p + 1];
            uint4 v0 = *(const uint4*)&H[(size_t)c0 * F + fo];
            uint4 v1 = *(const uint4*)&H[(size_t)c1 * F + fo];
            f16x2 h0 = as2(v0.x) + as2(v1.x);
            f16x2 h1 = as2(v0.y) + as2(v1.y);
            f16x2 h2 = as2(v0.z) + as2(v1.z);
            f16x2 h3 = as2(v0.w) + as2(v1.w);
            a[0] += (f32x2){(float)h0.x, (float)h0.y};
            a[1] += (f32x2){(float)h1.x, (float)h1.y};
            a[2] += (f32x2){(float)h2.x, (float)h2.y};
            a[3] += (f32x2){(float)h3.x, (float)h3.y};
            p += 2;
        }
        if (p < e) {
            int c = csr_col[p];
            uint4 v = *(const uint4*)&H[(size_t)c * F + fo];
            f16x2 h0 = as2(v.x), h1 = as2(v.y), h2 = as2(v.z), h3 = as2(v.w);
            a[0] += (f32x2){(float)h0.x, (float)h0.y};
            a[1] += (f32x2){(float)h1.x, (float)h1.y};
            a[2] += (f32x2){(float)h2.x, (float)h2.y};
            a[3] += (f32x2){(float)h3.x, (float)h3.y};
        }
        uint4 o = {pkrtz(a[0].x * di, a[0].y * di), pkrtz(a[1].x * di, a[1].y * di),
                   pkrtz(a[2].x * di, a[2].y * di), pkrtz(a[3].x * di, a[3].y * di)};
        *(uint4*)&xs[g * 136 + fo] = o;
    }
    __syncthreads();   // #1: xs complete

    // ---- phase B: MFMA Y^T = W @ g^T, split by output-feature across waves ----
    const int w = tid >> 6;        // wave 0..3 owns j in {2w, 2w+1}
    const int lane = tid & 63;
    const int q = lane >> 4;
    const int t = lane & 15;

    f16x8 xfr[4];
#pragma unroll
    for (int kk = 0; kk < 4; ++kk)
        xfr[kk] = *(const f16x8*)&xs[t * 136 + kk * 32 + q * 8];

    if (!OUT_F32) __syncthreads();   // #2: all xs reads done before ys overlay

    const int node = m0 + t;
    const float dv = deg_inv[node];
    const float mk = (dv > 0.f) ? 1.f : 0.f;

    f32x4 vout[2];
#pragma unroll
    for (int jj = 0; jj < 2; ++jj) {
        const int j = (w << 1) | jj;
        f32x4 acc = (f32x4){0.f, 0.f, 0.f, 0.f};
        const ushort* wrow = &Wh[(j * 16 + t) * F + q * 8];
#pragma unroll
        for (int kk = 0; kk < 4; ++kk) {
            f16x8 wfr = *(const f16x8*)&wrow[kk * 32];
            acc = __builtin_amdgcn_mfma_f32_16x16x32_f16(wfr, xfr[kk], acc, 0, 0, 0);
        }
        f32x4 bb = *(const f32x4*)&bias[j * 16 + q * 4];
        f32x4 v = acc + bb * mk;
        if (ELU) {
#pragma unroll
            for (int r = 0; r < 4; ++r) v[r] = (v[r] > 0.f) ? v[r] : expm1f(v[r]);
        }
        vout[jj] = v;
    }

    if (OUT_F32) {
        // wave's 128B per node = one full line: direct stores are line-complete
        float* of = &((float*)out)[(size_t)node * F + (w << 5) + q * 4];
        __builtin_nontemporal_store(vout[0], (f32x4*)of);
        __builtin_nontemporal_store(vout[1], (f32x4*)(of + 16));
    } else {
        // bounce through LDS (xs reused) -> 4KB contiguous store per block
        ushort* ys = xs;
        uint2 o0 = {pkrtz(vout[0][0], vout[0][1]), pkrtz(vout[0][2], vout[0][3])};
        uint2 o1 = {pkrtz(vout[1][0], vout[1][1]), pkrtz(vout[1][2], vout[1][3])};
        *(uint2*)&ys[t * 136 + (w << 5) + q * 4] = o0;
        *(uint2*)&ys[t * 136 + (w << 5) + 16 + q * 4] = o1;
        __syncthreads();   // #3
        const int n2 = tid >> 4, seg = tid & 15;
        uint4 vo = *(const uint4*)&ys[n2 * 136 + seg * 8];
        __builtin_nontemporal_store(*(f32x4*)&vo,
            (f32x4*)&((ushort*)out)[(size_t)(m0 + n2) * F + seg * 8]);
    }
}

// ---------------- launch ----------------

extern "C" void kernel_launch(void* const* d_in, const int* in_sizes, int n_in,
                              void* d_out, int out_size, void* d_ws, size_t ws_size,
                              hipStream_t stream) {
    const float* x  = (const float*)d_in[0];
    const int*   ei = (const int*)d_in[1];
    const float* W1 = (const float*)d_in[2];
    const float* b1 = (const float*)d_in[3];
    const float* W2 = (const float*)d_in[4];
    const float* b2 = (const float*)d_in[5];
    float* out = (float*)d_out;

    const int* row = ei;
    const int* col = ei + N_EDGES;

    // workspace layout (16B-aligned)
    ushort* bufA = (ushort*)d_ws;                            // N*F f16 (h1, 25.6 MB)
    ushort* bufB = bufA + (size_t)N_NODES * F;               // N*F f16 (Xh)
    int* csr_col = (int*)(bufB + (size_t)N_NODES * F);       // NBUCK*CAP (7.5 MB)
    int2* rs = (int2*)(csr_col + NBUCK * CAP);               // N {start,deg}
    float* deg_inv = (float*)(rs + N_NODES + 4);             // N
    int* bucket_cursor = (int*)(deg_inv + N_NODES);          // 512
    uint* W1h = (uint*)(bucket_cursor + 512);                // 8192 uints
    uint* W2h = W1h + F * F / 2;                             // 8192 uints
    int* pairs = (int*)bufA;  // 7.5 MB overlay, dead before fused layer 1 writes bufA

    // build + converts (converts backfill bucketize's idle CUs)
    (void)hipMemsetAsync(bucket_cursor, 0, 512 * sizeof(int), stream);
    build_convert_kernel<<<NBUCK + XCH512 + WCH512, 512, 0, stream>>>(
        row, col, bucket_cursor, pairs, x, W1, W2, (uint*)bufB, W1h, W2h);
    csr_finalize_kernel<<<NBUCK, 1024, 0, stream>>>(pairs, bucket_cursor, csr_col, rs, deg_inv);

    const int fb = N_NODES / 16;   // 6250, exact
    // layer 1: h1 = elu( agg(Xh) @ W1^T + mask*b1 ), f16 out
    fused_agg_gemm_kernel<true, false><<<fb, 256, 0, stream>>>(
        (const ushort*)bufB, rs, csr_col, deg_inv, (const ushort*)W1h, b1, bufA);
    // layer 2: out = agg(h1) @ W2^T + mask*b2, f32 out
    fused_agg_gemm_kernel<false, true><<<fb, 256, 0, stream>>>(
        bufA, rs, csr_col, deg_inv, (const ushort*)W2h, b2, out);
}